// Round 3
// baseline (207.451 us; speedup 1.0000x reference)
//
#include <hip/hip_runtime.h>
#include <hip/hip_fp16.h>

// BuildK: per-pixel K=48 neighbor softmax of -sqrt(mean((u_j - u_nbr)^2) + eps)
// R3: dist kernel restructured — 4 pixels per wave, 16 lanes per pixel, 3
// neighbors per lane (all 64 lanes active, 3 gathers in flight per lane).
// Distance via packed-half subtract + v_dot2_f32_f16 (fp32 accumulate):
// ~32 VALU ops/neighbor instead of ~96. Transpose kernel left UNCHANGED to
// A/B-test the ~82 us of non-dist time (fixed-overhead hypothesis).

#define EPS 1e-9f

typedef _Float16 h2 __attribute__((ext_vector_type(2)));
union V16 { uint4 u; h2 h[4]; };

__global__ __launch_bounds__(256) void transpose_half_kernel(
    const float* __restrict__ in, _Float16* __restrict__ UU, int N) {
  const int p = blockIdx.x * 256 + threadIdx.x;
  if (p >= N) return;
  __half h[32];
#pragma unroll
  for (int f = 0; f < 32; ++f) h[f] = __float2half_rn(in[(size_t)f * N + p]);
  uint4* dst = (uint4*)(UU + (size_t)p * 32);
#pragma unroll
  for (int r = 0; r < 4; ++r) {
    __half2 a = __halves2half2(h[8 * r + 0], h[8 * r + 1]);
    __half2 b = __halves2half2(h[8 * r + 2], h[8 * r + 3]);
    __half2 c = __halves2half2(h[8 * r + 4], h[8 * r + 5]);
    __half2 d = __halves2half2(h[8 * r + 6], h[8 * r + 7]);
    dst[r] = make_uint4(*(unsigned*)&a, *(unsigned*)&b, *(unsigned*)&c, *(unsigned*)&d);
  }
}

__device__ __forceinline__ float dot2acc(h2 d, float s) {
#if __has_builtin(__builtin_amdgcn_fdot2)
  return __builtin_amdgcn_fdot2(d, d, s, false);
#else
  float x = (float)d.x, y = (float)d.y;
  return s + x * x + y * y;
#endif
}

__global__ __launch_bounds__(256) void dist_softmax_kernel(
    const _Float16* __restrict__ UU, const int* __restrict__ idx,
    float* __restrict__ out, int J) {
  const int tid = threadIdx.x;
  const int wave = blockIdx.x * 4 + (tid >> 6);
  const int lane = tid & 63;
  const int g = lane >> 4;    // pixel subgroup 0..3 within wave
  const int sub = lane & 15;  // lane within subgroup
  const int j = wave * 4 + g; // pixel index
  if (j >= J) return;         // whole 16-lane group exits together

  // neighbor indices: lane handles k = sub, sub+16, sub+32 (coalesced reads)
  const int* ij = idx + (size_t)j * 48;
  const int n0 = ij[sub];
  const int n1 = ij[sub + 16];
  const int n2 = ij[sub + 32];

  const V16* uj = (const V16*)(UU + (size_t)j * 32);
  const V16* q0 = (const V16*)(UU + (size_t)n0 * 32);
  const V16* q1 = (const V16*)(UU + (size_t)n1 * 32);
  const V16* q2 = (const V16*)(UU + (size_t)n2 * 32);

  // issue all loads up front: 4 broadcast + 12 gather dwordx4 in flight
  V16 a[4], b0[4], b1[4], b2[4];
#pragma unroll
  for (int r = 0; r < 4; ++r) a[r].u = uj[r].u;
#pragma unroll
  for (int r = 0; r < 4; ++r) b0[r].u = q0[r].u;
#pragma unroll
  for (int r = 0; r < 4; ++r) b1[r].u = q1[r].u;
#pragma unroll
  for (int r = 0; r < 4; ++r) b2[r].u = q2[r].u;

  float s0 = 0.f, s1 = 0.f, s2 = 0.f;
#pragma unroll
  for (int r = 0; r < 4; ++r) {
#pragma unroll
    for (int i = 0; i < 4; ++i) {
      const h2 av = a[r].h[i];
      h2 d0 = av - b0[r].h[i];
      h2 d1 = av - b1[r].h[i];
      h2 d2 = av - b2[r].h[i];
      s0 = dot2acc(d0, s0);
      s1 = dot2acc(d1, s1);
      s2 = dot2acc(d2, s2);
    }
  }

  float D0 = -sqrtf(s0 * (1.0f / 32.0f) + EPS);
  float D1 = -sqrtf(s1 * (1.0f / 32.0f) + EPS);
  float D2 = -sqrtf(s2 * (1.0f / 32.0f) + EPS);

  // softmax over the 48 values held 3-per-lane across the 16-lane subgroup
  float m = fmaxf(D0, fmaxf(D1, D2));
#pragma unroll
  for (int off = 8; off; off >>= 1) m = fmaxf(m, __shfl_xor(m, off));
  float e0 = __expf(D0 - m);
  float e1 = __expf(D1 - m);
  float e2 = __expf(D2 - m);
  float t = e0 + e1 + e2;
#pragma unroll
  for (int off = 8; off; off >>= 1) t += __shfl_xor(t, off);
  const float inv = 1.0f / t;

  float* oj = out + (size_t)j * 48;
  oj[sub] = e0 * inv;
  oj[sub + 16] = e1 * inv;
  oj[sub + 32] = e2 * inv;
}

extern "C" void kernel_launch(void* const* d_in, const int* in_sizes, int n_in,
                              void* d_out, int out_size, void* d_ws, size_t ws_size,
                              hipStream_t stream) {
  const float* in1 = (const float*)d_in[0];
  const int* idx = (const int*)d_in[1];  // harness delivers integer inputs as int32
  float* out = (float*)d_out;
  _Float16* UU = (_Float16*)d_ws;        // N*32 halfs = 9.4 MB scratch

  const int N = in_sizes[0] / 32;        // 147456
  const int J = in_sizes[1] / 48;        // 147456

  transpose_half_kernel<<<(N + 255) / 256, 256, 0, stream>>>(in1, UU, N);

  // 16 pixels per 256-thread block (4 waves x 4 pixels)
  dist_softmax_kernel<<<(J + 15) / 16, 256, 0, stream>>>(UU, idx, out, J);
}

// Round 4
// 163.830 us; speedup vs baseline: 1.2663x; 1.2663x over previous
//
#include <hip/hip_runtime.h>
#include <hip/hip_fp16.h>

// BuildK: per-pixel K=48 neighbor softmax of -sqrt(mean((u_j - u_nbr)^2) + eps)
// R4: back to ONE WAVE PER PIXEL (R2's memory behavior), but quad-cooperative
// gathers: 4 lanes each load one 16-B chunk of a neighbor's 64-B fp16 vector,
// so the coalescer emits one 64-B request per neighbor (4x fewer TCC
// transactions than R2's per-lane 4x16B). All 64 lanes active. Distance via
// packed-half sub + v_dot2_f32_f16, quad-reduce via shfl_xor(1,2), softmax
// across quads via shfl_xor(4,8,16,32). Transpose unchanged (residual time is
// harness reset, established R1-R3).

#define EPS 1e-9f

typedef _Float16 h2 __attribute__((ext_vector_type(2)));
union V16 { uint4 u; h2 h[4]; };

__global__ __launch_bounds__(256) void transpose_half_kernel(
    const float* __restrict__ in, _Float16* __restrict__ UU, int N) {
  const int p = blockIdx.x * 256 + threadIdx.x;
  if (p >= N) return;
  __half h[32];
#pragma unroll
  for (int f = 0; f < 32; ++f) h[f] = __float2half_rn(in[(size_t)f * N + p]);
  uint4* dst = (uint4*)(UU + (size_t)p * 32);
#pragma unroll
  for (int r = 0; r < 4; ++r) {
    __half2 a = __halves2half2(h[8 * r + 0], h[8 * r + 1]);
    __half2 b = __halves2half2(h[8 * r + 2], h[8 * r + 3]);
    __half2 c = __halves2half2(h[8 * r + 4], h[8 * r + 5]);
    __half2 d = __halves2half2(h[8 * r + 6], h[8 * r + 7]);
    dst[r] = make_uint4(*(unsigned*)&a, *(unsigned*)&b, *(unsigned*)&c, *(unsigned*)&d);
  }
}

__device__ __forceinline__ float dot2acc(h2 d, float s) {
#if __has_builtin(__builtin_amdgcn_fdot2)
  return __builtin_amdgcn_fdot2(d, d, s, false);
#else
  float x = (float)d.x, y = (float)d.y;
  return s + x * x + y * y;
#endif
}

__global__ __launch_bounds__(256) void dist_softmax_kernel(
    const _Float16* __restrict__ UU, const int* __restrict__ idx,
    float* __restrict__ out, int J) {
  const int wave = blockIdx.x * 4 + (threadIdx.x >> 6);  // pixel j
  const int lane = threadIdx.x & 63;
  if (wave >= J) return;
  const int quad = lane >> 2;  // neighbor slot within a pass (0..15)
  const int q = lane & 3;      // 16-B chunk within the 64-B vector

  // own-pixel chunk: 8 features (16 B) — 4 distinct lines/wave, L2-hot
  V16 a;
  a.u = *(const uint4*)(UU + (size_t)wave * 32 + q * 8);

  // neighbor indices for the 3 passes (quad-redundant dword reads, 64 B/instr)
  const int* ij = idx + (size_t)wave * 48;
  const int n0 = ij[quad];
  const int n1 = ij[16 + quad];
  const int n2 = ij[32 + quad];

  // quad-cooperative gathers: per instruction, wave covers 16 neighbors as
  // 16 contiguous 64-B segments -> one 64-B request per neighbor
  V16 b0, b1, b2;
  b0.u = *(const uint4*)(UU + (size_t)n0 * 32 + q * 8);
  b1.u = *(const uint4*)(UU + (size_t)n1 * 32 + q * 8);
  b2.u = *(const uint4*)(UU + (size_t)n2 * 32 + q * 8);

  float s0 = 0.f, s1 = 0.f, s2 = 0.f;
#pragma unroll
  for (int i = 0; i < 4; ++i) {
    const h2 av = a.h[i];
    h2 d0 = av - b0.h[i];
    h2 d1 = av - b1.h[i];
    h2 d2 = av - b2.h[i];
    s0 = dot2acc(d0, s0);
    s1 = dot2acc(d1, s1);
    s2 = dot2acc(d2, s2);
  }
  // reduce 8-feature partials across the 4 chunks of the quad
  s0 += __shfl_xor(s0, 1); s0 += __shfl_xor(s0, 2);
  s1 += __shfl_xor(s1, 1); s1 += __shfl_xor(s1, 2);
  s2 += __shfl_xor(s2, 1); s2 += __shfl_xor(s2, 2);

  const float D0 = -sqrtf(s0 * (1.0f / 32.0f) + EPS);
  const float D1 = -sqrtf(s1 * (1.0f / 32.0f) + EPS);
  const float D2 = -sqrtf(s2 * (1.0f / 32.0f) + EPS);

  // softmax over 48 values: 3 per quad, quads redundant -> reduce across quads
  float m = fmaxf(D0, fmaxf(D1, D2));
#pragma unroll
  for (int off = 4; off < 64; off <<= 1) m = fmaxf(m, __shfl_xor(m, off));
  const float e0 = __expf(D0 - m);
  const float e1 = __expf(D1 - m);
  const float e2 = __expf(D2 - m);
  float t = e0 + e1 + e2;
#pragma unroll
  for (int off = 4; off < 64; off <<= 1) t += __shfl_xor(t, off);
  const float inv = 1.0f / t;

  // lanes with q==0 write their quad's 3 weights: 16 contiguous dwords/instr
  if (q == 0) {
    float* oj = out + (size_t)wave * 48;
    oj[quad] = e0 * inv;
    oj[16 + quad] = e1 * inv;
    oj[32 + quad] = e2 * inv;
  }
}

extern "C" void kernel_launch(void* const* d_in, const int* in_sizes, int n_in,
                              void* d_out, int out_size, void* d_ws, size_t ws_size,
                              hipStream_t stream) {
  const float* in1 = (const float*)d_in[0];
  const int* idx = (const int*)d_in[1];  // harness delivers integer inputs as int32
  float* out = (float*)d_out;
  _Float16* UU = (_Float16*)d_ws;        // N*32 halfs = 9.4 MB scratch

  const int N = in_sizes[0] / 32;        // 147456
  const int J = in_sizes[1] / 48;        // 147456

  transpose_half_kernel<<<(N + 255) / 256, 256, 0, stream>>>(in1, UU, N);

  // one wave per pixel, 4 waves per block
  dist_softmax_kernel<<<(J + 3) / 4, 256, 0, stream>>>(UU, idx, out, J);
}